// Round 2
// baseline (530.471 us; speedup 1.0000x reference)
//
#include <hip/hip_runtime.h>
#include <hip/hip_bf16.h>
#include <stdint.h>

#define K_DIM 20000
#define N_DIM 512
#define M_DIM 2048

#define BM 128
#define BN 128
#define BK 32              // 32 bf16 = 64 B per LDS row, 4 x 16B chunks
#define NSTEPS 625         // K_DIM / BK (exact)
#define SPLITS 20          // 64 tiles * 20 = 1280 blocks = 5 blocks/CU
#define GEMM_THREADS 256

typedef __bf16 bf16_t;
typedef bf16_t  bf16x8 __attribute__((ext_vector_type(8)));
typedef float   f32x4  __attribute__((ext_vector_type(4)));
typedef uint32_t u32x4 __attribute__((ext_vector_type(4)));

__device__ __forceinline__ uint32_t pack_bf16x2(float a, float b) {
  uint32_t ua = (uint32_t)__builtin_bit_cast(uint16_t, (bf16_t)a);
  uint32_t ub = (uint32_t)__builtin_bit_cast(uint16_t, (bf16_t)b);
  return ua | (ub << 16);
}

// XOR-swizzled LDS offset (in ushorts). Row = 64 B = 4 chunks of 16 B.
// chunk' = chunk ^ ((row>>1)&3): verified 8-lane subgroups of both the
// b128 staging writes and the b128 fragment reads hit 8 distinct 16B bank
// groups -> conflict-free (2 lanes/bank is free).
__device__ __forceinline__ int swz(int row, int chunk) {
  return row * 32 + ((chunk ^ ((row >> 1) & 3)) << 3);
}

// ---------------------------------------------------------------------------
// Kernel 0: E (K x N fp32, row-major) -> Bt (N x K bf16, row-major)
// ---------------------------------------------------------------------------
__global__ __launch_bounds__(256)
void bt_transpose_kernel(const float* __restrict__ B, uint16_t* __restrict__ Bt) {
  const int kb = blockIdx.x;      // 0..624
  const int nb = blockIdx.y;      // 0..7
  const int t  = threadIdx.x;
  const int rn = t >> 2;          // 0..63 local n
  const int kc = t & 3;           // 0..3  (8 k each)
  const int n  = nb * 64 + rn;
  const int kk = kb * 32 + kc * 8;

  float v[8];
#pragma unroll
  for (int j = 0; j < 8; ++j)
    v[j] = B[(size_t)(kk + j) * N_DIM + n];

  u32x4 q;
#pragma unroll
  for (int j = 0; j < 4; ++j)
    q[j] = pack_bf16x2(v[2 * j], v[2 * j + 1]);

  *reinterpret_cast<u32x4*>(&Bt[(size_t)n * K_DIM + kk]) = q;
}

// ---------------------------------------------------------------------------
// Kernel 1: out[m][n] = bias[n]   (accumulation target for split-K atomics)
// ---------------------------------------------------------------------------
__global__ __launch_bounds__(256)
void init_out_kernel(const float* __restrict__ bias, float* __restrict__ out) {
  const int i = blockIdx.x * 256 + threadIdx.x;
  out[i] = bias[i & (N_DIM - 1)];
}

// ---------------------------------------------------------------------------
// Kernel 2: split-K bf16 MFMA GEMM, 128x128 tile, 4 waves (2x2), BK=32,
// double-buffered XOR-swizzled LDS (32 KB total -> 5 blocks/CU).
// grid = 64 tiles * 20 K-splits = 1280 blocks.
// ---------------------------------------------------------------------------
__global__ __launch_bounds__(GEMM_THREADS, 5)
void gemm_split_kernel(const float* __restrict__ X,
                       const uint16_t* __restrict__ Bt,
                       float* __restrict__ out) {
  __shared__ __align__(16) uint16_t Al[2][BM * 32];   // 16 KB
  __shared__ __align__(16) uint16_t Bl[2][BN * 32];   // 16 KB

  const int bid  = blockIdx.x;
  const int s    = bid >> 6;       // K-split 0..19
  const int tile = bid & 63;
  const int mt   = tile & 15;
  const int nt   = tile >> 4;      // 0..3
  const int m0 = mt * BM;
  const int n0 = nt * BN;
  const int step0 = (s * NSTEPS) / SPLITS;
  const int step1 = ((s + 1) * NSTEPS) / SPLITS;
  const int nsteps = step1 - step0;   // 31 or 32

  const int t    = threadIdx.x;
  const int wid  = t >> 6;
  const int lane = t & 63;
  const int wr  = (wid >> 1) * 64;  // wave row offset in tile
  const int wc  = (wid & 1) * 64;   // wave col offset in tile
  const int l15 = lane & 15;
  const int l16 = lane >> 4;        // 0..3

  // staging decomposition: thread owns one 16B chunk of one row per pass
  const int srow = t >> 2;          // 0..63 (+64 on second pass)
  const int sch  = t & 3;           // chunk 0..3 (8 bf16 / 8 fp32*?)

  const float*    __restrict__ xptr  = X  + (size_t)(m0 + srow) * K_DIM + step0 * BK + sch * 8;
  const uint16_t* __restrict__ btptr = Bt + (size_t)(n0 + srow) * K_DIM + step0 * BK + sch * 8;

  f32x4 acc[4][4] = {};

  // prologue: stage step0 into buffer 0
  {
#pragma unroll
    for (int p = 0; p < 2; ++p) {
      f32x4 v0 = *reinterpret_cast<const f32x4*>(xptr + (size_t)p * 64 * K_DIM);
      f32x4 v1 = *reinterpret_cast<const f32x4*>(xptr + (size_t)p * 64 * K_DIM + 4);
      u32x4 w;
      w[0] = pack_bf16x2(v0[0], v0[1]);
      w[1] = pack_bf16x2(v0[2], v0[3]);
      w[2] = pack_bf16x2(v1[0], v1[1]);
      w[3] = pack_bf16x2(v1[2], v1[3]);
      *reinterpret_cast<u32x4*>(&Al[0][swz(p * 64 + srow, sch)]) = w;
      u32x4 bw = *reinterpret_cast<const u32x4*>(btptr + (size_t)p * 64 * K_DIM);
      *reinterpret_cast<u32x4*>(&Bl[0][swz(p * 64 + srow, sch)]) = bw;
    }
  }
  __syncthreads();

  int buf = 0;
  for (int i = 0; i < nsteps; ++i) {
    // issue next-step global loads early (land under MFMA)
    f32x4 av[2][2];
    u32x4 bv[2];
    const bool have = (i + 1 < nsteps);
    if (have) {
      const int koff = (i + 1) * BK;
#pragma unroll
      for (int p = 0; p < 2; ++p) {
        av[p][0] = *reinterpret_cast<const f32x4*>(xptr + (size_t)p * 64 * K_DIM + koff);
        av[p][1] = *reinterpret_cast<const f32x4*>(xptr + (size_t)p * 64 * K_DIM + koff + 4);
        bv[p]    = *reinterpret_cast<const u32x4*>(btptr + (size_t)p * 64 * K_DIM + koff);
      }
    }

    // compute current buffer
    bf16x8 afr[4], bfr[4];
#pragma unroll
    for (int mf = 0; mf < 4; ++mf)
      afr[mf] = *reinterpret_cast<const bf16x8*>(&Al[buf][swz(wr + mf * 16 + l15, l16)]);
#pragma unroll
    for (int nf = 0; nf < 4; ++nf)
      bfr[nf] = *reinterpret_cast<const bf16x8*>(&Bl[buf][swz(wc + nf * 16 + l15, l16)]);
#pragma unroll
    for (int mf = 0; mf < 4; ++mf)
#pragma unroll
      for (int nf = 0; nf < 4; ++nf)
        acc[mf][nf] = __builtin_amdgcn_mfma_f32_16x16x32_bf16(afr[mf], bfr[nf], acc[mf][nf], 0, 0, 0);

    // write next-step tiles into the other buffer
    if (have) {
      const int nbuf = buf ^ 1;
#pragma unroll
      for (int p = 0; p < 2; ++p) {
        u32x4 w;
        w[0] = pack_bf16x2(av[p][0][0], av[p][0][1]);
        w[1] = pack_bf16x2(av[p][0][2], av[p][0][3]);
        w[2] = pack_bf16x2(av[p][1][0], av[p][1][1]);
        w[3] = pack_bf16x2(av[p][1][2], av[p][1][3]);
        *reinterpret_cast<u32x4*>(&Al[nbuf][swz(p * 64 + srow, sch)]) = w;
        *reinterpret_cast<u32x4*>(&Bl[nbuf][swz(p * 64 + srow, sch)]) = bv[p];
      }
    }
    __syncthreads();
    buf ^= 1;
  }

  // epilogue: scaled atomic accumulation (C/D layout: col = lane&15, row = (lane>>4)*4 + j)
  const float scale = 1.0f / (float)K_DIM;
#pragma unroll
  for (int mf = 0; mf < 4; ++mf) {
#pragma unroll
    for (int nf = 0; nf < 4; ++nf) {
      const int row = m0 + wr + mf * 16 + l16 * 4;
      const int col = n0 + wc + nf * 16 + l15;
#pragma unroll
      for (int j = 0; j < 4; ++j)
        atomicAdd(&out[(size_t)(row + j) * N_DIM + col], acc[mf][nf][j] * scale);
    }
  }
}

// ---------------------------------------------------------------------------
extern "C" void kernel_launch(void* const* d_in, const int* in_sizes, int n_in,
                              void* d_out, int out_size, void* d_ws, size_t ws_size,
                              hipStream_t stream) {
  (void)in_sizes; (void)n_in; (void)out_size; (void)ws_size;
  const float* x    = (const float*)d_in[0];
  const float* emb  = (const float*)d_in[1];
  const float* bias = (const float*)d_in[2];
  float*    out = (float*)d_out;
  uint16_t* bt  = (uint16_t*)d_ws;   // 512*20000*2 = 20.48 MB

  bt_transpose_kernel<<<dim3(K_DIM / 32, N_DIM / 64), 256, 0, stream>>>(emb, bt);
  init_out_kernel<<<(M_DIM * N_DIM) / 256, 256, 0, stream>>>(bias, out);
  gemm_split_kernel<<<64 * SPLITS, GEMM_THREADS, 0, stream>>>(x, bt, out);
}

// Round 3
// 108.950 us; speedup vs baseline: 4.8690x; 4.8690x over previous
//
#include <hip/hip_runtime.h>
#include <hip/hip_bf16.h>
#include <stdint.h>

#define K_DIM 20000
#define N_DIM 512
#define M_DIM 2048

#define BM 128
#define BN 128
#define BK 32              // 32 bf16 = 64 B per LDS row = 4 x 16B chunks
#define NSTEPS 625         // K_DIM / BK (exact)
#define SPLITS 12          // 64 tiles * 12 = 768 blocks = 3 blocks/CU
#define GEMM_THREADS 256

typedef __bf16 bf16_t;
typedef bf16_t  bf16x8 __attribute__((ext_vector_type(8)));
typedef float   f32x4  __attribute__((ext_vector_type(4)));
typedef uint32_t u32x2 __attribute__((ext_vector_type(2)));
typedef uint32_t u32x4 __attribute__((ext_vector_type(4)));

__device__ __forceinline__ uint32_t pack_bf16x2(float a, float b) {
  uint32_t ua = (uint32_t)__builtin_bit_cast(uint16_t, (bf16_t)a);
  uint32_t ub = (uint32_t)__builtin_bit_cast(uint16_t, (bf16_t)b);
  return ua | (ub << 16);
}

// async global->LDS, 16B per lane. LDS dest must be wave-uniform base
// (HW writes base + lane*16 linearly); global src is per-lane.
__device__ __forceinline__ void gload16(const uint16_t* g, uint16_t* l) {
  __builtin_amdgcn_global_load_lds(
      (const __attribute__((address_space(1))) void*)g,
      (__attribute__((address_space(3))) void*)l, 16, 0, 0);
}

// ---------------------------------------------------------------------------
// Kernel 0: E (K x N fp32, row-major) -> Bt (N x K bf16, row-major)
// ---------------------------------------------------------------------------
__global__ __launch_bounds__(256)
void bt_transpose_kernel(const float* __restrict__ B, uint16_t* __restrict__ Bt) {
  const int kb = blockIdx.x;      // 0..624
  const int nb = blockIdx.y;      // 0..7
  const int t  = threadIdx.x;
  const int rn = t >> 2;          // 0..63 local n
  const int kc = t & 3;           // 0..3  (8 k each)
  const int n  = nb * 64 + rn;
  const int kk = kb * 32 + kc * 8;

  float v[8];
#pragma unroll
  for (int j = 0; j < 8; ++j)
    v[j] = B[(size_t)(kk + j) * N_DIM + n];

  u32x4 q;
#pragma unroll
  for (int j = 0; j < 4; ++j)
    q[j] = pack_bf16x2(v[2 * j], v[2 * j + 1]);

  *reinterpret_cast<u32x4*>(&Bt[(size_t)n * K_DIM + kk]) = q;
}

// ---------------------------------------------------------------------------
// Kernel 1: out[m][n] = bias[n]   (accumulation target for split-K atomics)
// ---------------------------------------------------------------------------
__global__ __launch_bounds__(256)
void init_out_kernel(const float* __restrict__ bias, float* __restrict__ out) {
  const int i = blockIdx.x * 256 + threadIdx.x;
  out[i] = bias[i & (N_DIM - 1)];
}

// ---------------------------------------------------------------------------
// Kernel 2: split-K bf16 MFMA GEMM, 128x128 tile, 4 waves (2x2), BK=32.
// A: fp32 global -> reg convert -> swizzled ds_write (double-buffered 16 KB)
// B: global_load_lds 16B, pre-swizzled per-lane source, linear LDS dest
//    (double-buffered 16 KB). Total LDS 32 KB -> 3 blocks/CU at grid 768.
// LDS swizzle: 16B chunk c at row r lives at phys chunk c ^ ((r>>1)&3);
// verified conflict-free for b128 frag reads and staging writes.
// ---------------------------------------------------------------------------
__global__ __launch_bounds__(GEMM_THREADS)
void gemm_split_kernel(const float* __restrict__ X,
                       const uint16_t* __restrict__ Bt,
                       float* __restrict__ out) {
  __shared__ __align__(16) uint16_t Al[2][BM * 32];   // 8 KB each
  __shared__ __align__(16) uint16_t Bl[2][BN * 32];   // 8 KB each

  const int bid  = blockIdx.x;
  const int s    = bid >> 6;       // K-split 0..SPLITS-1
  const int tile = bid & 63;
  const int mt   = tile & 15;
  const int nt   = tile >> 4;      // 0..3
  const int m0 = mt * BM;
  const int n0 = nt * BN;
  const int step0 = (s * NSTEPS) / SPLITS;
  const int step1 = ((s + 1) * NSTEPS) / SPLITS;
  const int nsteps = step1 - step0;   // 52 or 53

  const int t    = threadIdx.x;
  const int wid  = t >> 6;
  const int lane = t & 63;
  const int wr  = (wid >> 1) * 64;  // wave row offset in tile
  const int wc  = (wid & 1) * 64;   // wave col offset in tile
  const int l15 = lane & 15;
  const int l16 = lane >> 4;        // 0..3

  // --- A staging decomposition: 4 passes of 32 rows, 8 lanes x 16B per row
  const int arow = t >> 3;          // 0..31
  const int af4  = t & 7;           // fp32x4 chunk in row (8 x 16B fp32 = 128B)
  const int aswz = (arow >> 1) & 3; // invariant under row+32p
  const int aoff = ((af4 >> 1) ^ aswz) * 8 + (af4 & 1) * 4;  // ushort offset in row
  const float* __restrict__ xptr = X + (size_t)(m0 + arow) * K_DIM + step0 * BK + af4 * 4;

  // --- B gload_lds decomposition: wave w, call q covers rows w*32+q*16..+16
  const int brow0 = wid * 32 + (lane >> 2);        // rows for q=0 (q=1: +16)
  const int bch   = (lane & 3) ^ ((brow0 >> 1) & 3); // src chunk (swizzle inv.)
  const uint16_t* __restrict__ bsrc0 =
      Bt + (size_t)(n0 + brow0) * K_DIM + step0 * BK + bch * 8;
  const uint16_t* __restrict__ bsrc1 = bsrc0 + (size_t)16 * K_DIM;
  const int bdst0 = wid * 1024;     // ushort offset of wave's q=0 chunk
  const int bdst1 = bdst0 + 512;

  // --- frag read offsets (chunk swizzle is mf/nf-invariant)
  const int rsw   = ((l15 >> 1) & 3);
  const int fchunk = ((l16 ^ rsw) << 3);

  f32x4 acc[4][4] = {};

  // prologue: stage step0 into buffer 0
  gload16(bsrc0, &Bl[0][bdst0]);
  gload16(bsrc1, &Bl[0][bdst1]);
#pragma unroll
  for (int p = 0; p < 4; ++p) {
    f32x4 v = *reinterpret_cast<const f32x4*>(xptr + (size_t)p * 32 * K_DIM);
    u32x2 w;
    w[0] = pack_bf16x2(v[0], v[1]);
    w[1] = pack_bf16x2(v[2], v[3]);
    *reinterpret_cast<u32x2*>(&Al[0][(arow + p * 32) * 32 + aoff]) = w;
  }
  __syncthreads();

  int buf = 0;
  for (int i = 0; i < nsteps; ++i) {
    const bool have = (i + 1 < nsteps);
    const int nbuf = buf ^ 1;
    f32x4 av[4];
    if (have) {
      const int koff = (i + 1) * BK;
      // B: async direct-to-LDS (in flight across the MFMA block)
      gload16(bsrc0 + koff, &Bl[nbuf][bdst0]);
      gload16(bsrc1 + koff, &Bl[nbuf][bdst1]);
      // A: issue fp32 loads early
#pragma unroll
      for (int p = 0; p < 4; ++p)
        av[p] = *reinterpret_cast<const f32x4*>(xptr + (size_t)p * 32 * K_DIM + koff);
    }

    // compute current buffer
    bf16x8 afr[4], bfr[4];
#pragma unroll
    for (int mf = 0; mf < 4; ++mf)
      afr[mf] = *reinterpret_cast<const bf16x8*>(&Al[buf][(wr + mf * 16 + l15) * 32 + fchunk]);
#pragma unroll
    for (int nf = 0; nf < 4; ++nf)
      bfr[nf] = *reinterpret_cast<const bf16x8*>(&Bl[buf][(wc + nf * 16 + l15) * 32 + fchunk]);
#pragma unroll
    for (int mf = 0; mf < 4; ++mf)
#pragma unroll
      for (int nf = 0; nf < 4; ++nf)
        acc[mf][nf] = __builtin_amdgcn_mfma_f32_16x16x32_bf16(afr[mf], bfr[nf], acc[mf][nf], 0, 0, 0);

    // A: convert + swizzled write into the other buffer
    if (have) {
#pragma unroll
      for (int p = 0; p < 4; ++p) {
        u32x2 w;
        w[0] = pack_bf16x2(av[p][0], av[p][1]);
        w[1] = pack_bf16x2(av[p][2], av[p][3]);
        *reinterpret_cast<u32x2*>(&Al[nbuf][(arow + p * 32) * 32 + aoff]) = w;
      }
    }
    __syncthreads();   // drains vmcnt(0) (B gload_lds) + lgkmcnt (A writes)
    buf ^= 1;
  }

  // epilogue: scaled atomic accumulation (C/D: col = lane&15, row = (lane>>4)*4 + j)
  const float scale = 1.0f / (float)K_DIM;
#pragma unroll
  for (int mf = 0; mf < 4; ++mf) {
#pragma unroll
    for (int nf = 0; nf < 4; ++nf) {
      const int row = m0 + wr + mf * 16 + l16 * 4;
      const int col = n0 + wc + nf * 16 + l15;
#pragma unroll
      for (int j = 0; j < 4; ++j)
        atomicAdd(&out[(size_t)(row + j) * N_DIM + col], acc[mf][nf][j] * scale);
    }
  }
}

// ---------------------------------------------------------------------------
extern "C" void kernel_launch(void* const* d_in, const int* in_sizes, int n_in,
                              void* d_out, int out_size, void* d_ws, size_t ws_size,
                              hipStream_t stream) {
  (void)in_sizes; (void)n_in; (void)out_size; (void)ws_size;
  const float* x    = (const float*)d_in[0];
  const float* emb  = (const float*)d_in[1];
  const float* bias = (const float*)d_in[2];
  float*    out = (float*)d_out;
  uint16_t* bt  = (uint16_t*)d_ws;   // 512*20000*2 = 20.48 MB

  bt_transpose_kernel<<<dim3(K_DIM / 32, N_DIM / 64), 256, 0, stream>>>(emb, bt);
  init_out_kernel<<<(M_DIM * N_DIM) / 256, 256, 0, stream>>>(bias, out);
  gemm_split_kernel<<<64 * SPLITS, GEMM_THREADS, 0, stream>>>(x, bt, out);
}